// Round 4
// baseline (2220.107 us; speedup 1.0000x reference)
//
#include <hip/hip_runtime.h>
#include <math.h>

// ---- problem constants ----
constexpr int Bc  = 2;
constexpr int Lc  = 1024;
constexpr int BL  = Bc * Lc;    // 2048
constexpr int HS  = 2048;
constexpr int NH  = 8;
constexpr int HD  = 256;
constexpr int DV  = 512;
constexpr int KD  = NH * HD;    // 2048
constexpr int VD  = NH * DV;    // 4096
constexpr int NE  = 3;
constexpr int KSZ = 4;
constexpr int NCAT = 12288;     // Wq|Wk|Wv|Wg rows concatenated

__device__ __forceinline__ float sigf(float x) { return 1.f / (1.f + expf(-x)); }

__device__ __forceinline__ ushort f2bf(float f) {
  unsigned u = __float_as_uint(f);
  unsigned r = u + 0x7fffu + ((u >> 16) & 1u);
  return (ushort)(r >> 16);
}
__device__ __forceinline__ float bf2f(ushort u) {
  return __uint_as_float(((unsigned)u) << 16);
}

typedef __attribute__((ext_vector_type(8))) short bf16x8;
typedef __attribute__((ext_vector_type(4))) float f32x4;

#define AS1C(p) ((const __attribute__((address_space(1))) void*)(p))
#define AS3(p)  ((__attribute__((address_space(3))) void*)(p))

// =====================================================================
// fp32 -> bf16 (RNE) elementwise, vectorized x4
// =====================================================================
__global__ __launch_bounds__(256) void cvt_kernel(const float* __restrict__ in,
                                                  ushort* __restrict__ out, int n4) {
  int i = blockIdx.x * blockDim.x + threadIdx.x;
  if (i >= n4) return;
  float4 v = ((const float4*)in)[i];
  ushort4 o;
  o.x = f2bf(v.x); o.y = f2bf(v.y); o.z = f2bf(v.z); o.w = f2bf(v.w);
  ((ushort4*)out)[i] = o;
}

// fused 4-source weight conversion into contiguous Wcat (Wq|Wk|Wv|Wg)
__global__ __launch_bounds__(256) void cvt4_kernel(const float* __restrict__ wq,
    const float* __restrict__ wk, const float* __restrict__ wv,
    const float* __restrict__ wg, ushort* __restrict__ out) {
  const int s0 = KD * HS / 4, s1 = 2 * s0, s2 = s1 + VD * HS / 4, s3 = s2 + VD * HS / 4;
  int i = blockIdx.x * blockDim.x + threadIdx.x;
  if (i >= s3) return;
  const float* src;
  int j;
  if (i < s0)      { src = wq; j = i; }
  else if (i < s1) { src = wk; j = i - s0; }
  else if (i < s2) { src = wv; j = i - s1; }
  else             { src = wg; j = i - s2; }
  float4 v = ((const float4*)src)[j];
  ushort4 o;
  o.x = f2bf(v.x); o.y = f2bf(v.y); o.z = f2bf(v.z); o.w = f2bf(v.w);
  ((ushort4*)out)[i] = o;
}

// =====================================================================
// bf16 MFMA GEMM core: C[M,N] = A[M,K] * B[N,K]^T, bf16 inputs row-major,
// fp32 accumulate, output fp32 or bf16. 128x128 tile, BK=32, 4 waves (2x2
// of 64x64), m97 structure: global_load_lds width=16, XOR-swizzled LDS.
// =====================================================================
template<bool BF16OUT>
__device__ __forceinline__ void mfma_core(const ushort* __restrict__ A, int lda,
                                          const ushort* __restrict__ B, int ldb,
                                          void* __restrict__ Cv, int ldc,
                                          int K, int m0, int n0,
                                          ushort* As, ushort* Bs) {
  const int tid = threadIdx.x;
  const int w = tid >> 6, lane = tid & 63;
  const int wm = (w >> 1) << 6, wn = (w & 1) << 6;
  f32x4 acc[4][4];
#pragma unroll
  for (int i = 0; i < 4; i++)
#pragma unroll
    for (int j = 0; j < 4; j++) acc[i][j] = (f32x4){0.f, 0.f, 0.f, 0.f};

  const int rc = lane >> 2;                 // row within chunk 0..15
  const int slot = lane & 3;                // 16B slot within row
  const int r0 = (2 * w) * 16 + rc;
  const int r1 = (2 * w + 1) * 16 + rc;
  const int g0 = slot ^ (r0 & 3);           // XOR swizzle applied on global side
  const int g1 = slot ^ (r1 & 3);
  const ushort* A0 = A + (size_t)(m0 + r0) * lda + g0 * 8;
  const ushort* A1 = A + (size_t)(m0 + r1) * lda + g1 * 8;
  const ushort* B0 = B + (size_t)(n0 + r0) * ldb + g0 * 8;
  const ushort* B1 = B + (size_t)(n0 + r1) * ldb + g1 * 8;
  ushort* lA0 = As + (2 * w) * 512;
  ushort* lA1 = As + (2 * w + 1) * 512;
  ushort* lB0 = Bs + (2 * w) * 512;
  ushort* lB1 = Bs + (2 * w + 1) * 512;

  const int gi = ((lane >> 4) ^ (lane & 3)) << 3;
  const int fr = lane & 15;

  for (int k0 = 0; k0 < K; k0 += 32) {
    __builtin_amdgcn_global_load_lds(AS1C(A0 + k0), AS3(lA0), 16, 0, 0);
    __builtin_amdgcn_global_load_lds(AS1C(A1 + k0), AS3(lA1), 16, 0, 0);
    __builtin_amdgcn_global_load_lds(AS1C(B0 + k0), AS3(lB0), 16, 0, 0);
    __builtin_amdgcn_global_load_lds(AS1C(B1 + k0), AS3(lB1), 16, 0, 0);
    __syncthreads();
    bf16x8 af[4], bff[4];
#pragma unroll
    for (int i = 0; i < 4; i++) {
      af[i]  = *(const bf16x8*)&As[(wm + i * 16 + fr) * 32 + gi];
      bff[i] = *(const bf16x8*)&Bs[(wn + i * 16 + fr) * 32 + gi];
    }
#pragma unroll
    for (int i = 0; i < 4; i++)
#pragma unroll
      for (int j = 0; j < 4; j++)
        acc[i][j] = __builtin_amdgcn_mfma_f32_16x16x32_bf16(af[i], bff[j], acc[i][j], 0, 0, 0);
    __syncthreads();
  }
#pragma unroll
  for (int i = 0; i < 4; i++) {
#pragma unroll
    for (int r = 0; r < 4; r++) {
      int row = m0 + wm + i * 16 + (lane >> 4) * 4 + r;
#pragma unroll
      for (int j = 0; j < 4; j++) {
        int col = n0 + wn + j * 16 + fr;
        float val = acc[i][j][r];
        if (BF16OUT) ((ushort*)Cv)[(size_t)row * ldc + col] = f2bf(val);
        else         ((float*)Cv)[(size_t)row * ldc + col]  = val;
      }
    }
  }
}

__global__ __launch_bounds__(256) void gemm_big_kernel(const ushort* __restrict__ A,
    const ushort* __restrict__ B, ushort* __restrict__ C) {
  __shared__ ushort As[4096], Bs[4096];
  mfma_core<true>(A, HS, B, HS, C, NCAT, HS, blockIdx.y * 128, blockIdx.x * 128, As, Bs);
}

__global__ __launch_bounds__(256) void gemm_wo_kernel(const ushort* __restrict__ A,
    const ushort* __restrict__ B, float* __restrict__ C) {
  __shared__ ushort As[4096], Bs[4096];
  mfma_core<false>(A, VD, B, VD, C, HS, VD, blockIdx.y * 128, blockIdx.x * 128, As, Bs);
}

// ke[e, t, h*HD + c] = sum_d kbf[t, h*HD+d] * wek[e,h,c,d]   (z = e*NH+h)
__global__ __launch_bounds__(256) void gemm_ke_kernel(const ushort* __restrict__ kbf,
    const ushort* __restrict__ wek, float* __restrict__ ke) {
  __shared__ ushort As[4096], Bs[4096];
  int z = blockIdx.z, e = z >> 3, h = z & 7;
  mfma_core<false>(kbf + h * HD, KD, wek + (size_t)z * HD * HD, HD,
                   ke + (size_t)e * BL * KD + h * HD, KD, HD,
                   blockIdx.y * 128, blockIdx.x * 128, As, Bs);
}

// =====================================================================
// fp32 GEMM (small N: fused Wb|Wa projection), 64x64 tile
// =====================================================================
__global__ __launch_bounds__(256) void gemm_nt_kernel(const float* __restrict__ A,
    const float* __restrict__ W, float* __restrict__ C, int M, int N, int K) {
  __shared__ float As[16*68];
  __shared__ float Ws[16*68];
  const int tid = threadIdx.x;
  const int m0 = blockIdx.y * 64, n0 = blockIdx.x * 64;
  const int tx = tid & 15, ty = tid >> 4;
  const int lr = tid >> 2;
  const int lc = (tid & 3) << 2;
  float acc[4][4] = {{0.f,0.f,0.f,0.f},{0.f,0.f,0.f,0.f},{0.f,0.f,0.f,0.f},{0.f,0.f,0.f,0.f}};
  for (int k0 = 0; k0 < K; k0 += 16) {
    float4 av = make_float4(0.f,0.f,0.f,0.f), wv = make_float4(0.f,0.f,0.f,0.f);
    if (m0 + lr < M) av = *(const float4*)&A[(size_t)(m0 + lr) * K + k0 + lc];
    if (n0 + lr < N) wv = *(const float4*)&W[(size_t)(n0 + lr) * K + k0 + lc];
    __syncthreads();
    As[(lc+0)*68 + lr] = av.x; As[(lc+1)*68 + lr] = av.y;
    As[(lc+2)*68 + lr] = av.z; As[(lc+3)*68 + lr] = av.w;
    Ws[(lc+0)*68 + lr] = wv.x; Ws[(lc+1)*68 + lr] = wv.y;
    Ws[(lc+2)*68 + lr] = wv.z; Ws[(lc+3)*68 + lr] = wv.w;
    __syncthreads();
#pragma unroll
    for (int kk = 0; kk < 16; kk++) {
      float4 a4 = *(const float4*)&As[kk*68 + ty*4];
      float4 w4 = *(const float4*)&Ws[kk*68 + tx*4];
      float ar[4] = {a4.x, a4.y, a4.z, a4.w};
      float wr[4] = {w4.x, w4.y, w4.z, w4.w};
#pragma unroll
      for (int i = 0; i < 4; i++)
#pragma unroll
        for (int j = 0; j < 4; j++)
          acc[i][j] = fmaf(ar[i], wr[j], acc[i][j]);
    }
  }
#pragma unroll
  for (int i = 0; i < 4; i++) {
    int m = m0 + ty*4 + i;
    if (m >= M) continue;
#pragma unroll
    for (int j = 0; j < 4; j++) {
      int n = n0 + tx*4 + j;
      if (n < N) C[(size_t)m * N + n] = acc[i][j];
    }
  }
}

// =====================================================================
// causal depthwise conv (K=4) + SiLU. x: bf16 [BL, ldx] strided view.
// y: f32 [BL,C] if obf==0, bf16 [BL,C] if obf==1.
// =====================================================================
__global__ __launch_bounds__(256) void conv_silu_kernel(const ushort* __restrict__ x, int ldx,
    const float* __restrict__ w, void* __restrict__ y, int C, int obf) {
  int idx = blockIdx.x * blockDim.x + threadIdx.x;
  int nc4 = C >> 2;
  if (idx >= BL * nc4) return;
  int c4 = (idx % nc4) << 2;
  int t  = idx / nc4;
  int b = t / Lc, l = t % Lc;
  float4 w0 = *(const float4*)&w[(c4+0)*KSZ];
  float4 w1 = *(const float4*)&w[(c4+1)*KSZ];
  float4 w2 = *(const float4*)&w[(c4+2)*KSZ];
  float4 w3 = *(const float4*)&w[(c4+3)*KSZ];
  const float* p0 = (const float*)&w0; const float* p1 = (const float*)&w1;
  const float* p2 = (const float*)&w2; const float* p3 = (const float*)&w3;
  float4 acc = make_float4(0.f,0.f,0.f,0.f);
#pragma unroll
  for (int i = 0; i < KSZ; i++) {
    int ls = l - (KSZ - 1) + i;
    if (ls < 0) continue;
    ushort4 xu = *(const ushort4*)&x[(size_t)(b * Lc + ls) * ldx + c4];
    acc.x = fmaf(bf2f(xu.x), p0[i], acc.x);
    acc.y = fmaf(bf2f(xu.y), p1[i], acc.y);
    acc.z = fmaf(bf2f(xu.z), p2[i], acc.z);
    acc.w = fmaf(bf2f(xu.w), p3[i], acc.w);
  }
  acc.x *= sigf(acc.x); acc.y *= sigf(acc.y); acc.z *= sigf(acc.z); acc.w *= sigf(acc.w);
  if (obf) {
    ushort4 o;
    o.x = f2bf(acc.x); o.y = f2bf(acc.y); o.z = f2bf(acc.z); o.w = f2bf(acc.w);
    *(ushort4*)&((ushort*)y)[(size_t)t * C + c4] = o;
  } else {
    *(float4*)&((float*)y)[(size_t)t * C + c4] = acc;
  }
}

// =====================================================================
// l2norm over last dim (HD=256), one wave per row, * scale.
// out: f32 (obf=0, may alias in) or bf16 (obf=1).
// =====================================================================
__global__ __launch_bounds__(256) void l2norm_kernel(const float* __restrict__ in,
    void* __restrict__ outp, float scale, int rows, int obf) {
  int wid = threadIdx.x >> 6, lane = threadIdx.x & 63;
  int row = (blockIdx.x << 2) + wid;
  if (row >= rows) return;
  const float* p = in + (size_t)row * HD;
  float4 a = *(const float4*)&p[lane * 4];
  float ss = a.x*a.x + a.y*a.y + a.z*a.z + a.w*a.w;
#pragma unroll
  for (int off = 32; off >= 1; off >>= 1) ss += __shfl_xor(ss, off, 64);
  float r = rsqrtf(ss + 1e-6f) * scale;
  a.x *= r; a.y *= r; a.z *= r; a.w *= r;
  if (obf) {
    ushort4 o;
    o.x = f2bf(a.x); o.y = f2bf(a.y); o.z = f2bf(a.z); o.w = f2bf(a.w);
    *(ushort4*)&((ushort*)outp)[(size_t)row * HD + lane * 4] = o;
  } else {
    *(float4*)&((float*)outp)[(size_t)row * HD + lane * 4] = a;
  }
}

// =====================================================================
// per-token gate scalars from fused xba[t][48] (b: cols 0..23, a: 24..47)
// =====================================================================
__global__ __launch_bounds__(256) void scalars_kernel(const float* __restrict__ xba,
    const int* __restrict__ modality,
    const float* __restrict__ A_log, const float* __restrict__ dt_bias,
    float* __restrict__ dec, float* __restrict__ bm) {
  int idx = blockIdx.x * blockDim.x + threadIdx.x;
  if (idx >= BL * NE * NH) return;
  int eh = idx % (NE * NH);
  int t  = idx / (NE * NH);
  int e = eh / NH, h = eh % NH;
  float a    = xba[(size_t)t * 48 + 24 + eh];
  float beta = sigf(xba[(size_t)t * 48 + eh]);
  int md = modality[t];
  float m = (e == 0) ? 1.f : ((e == 1) ? (md == 0 ? 1.f : 0.f) : (md == 1 ? 1.f : 0.f));
  float spin = a + dt_bias[eh];
  float sp = (spin > 20.f) ? spin : log1pf(expf(spin));
  float g = -expf(A_log[eh]) * sp;
  float d = m * expf(g) + (1.f - m);
  int b = t / Lc, l = t % Lc;
  size_t off = ((size_t)(e * Bc + b) * NH + h) * Lc + l;
  dec[off] = d;
  bm[off]  = beta * m;
}

__global__ void wout_kernel(const float* __restrict__ ow, float* __restrict__ wout) {
  int h = threadIdx.x;
  if (h >= NH) return;
  float e0 = ow[0*NH + h], e1 = ow[1*NH + h], e2 = ow[2*NH + h];
  float mx = fmaxf(e0, fmaxf(e1, e2));
  float x0 = expf(e0 - mx), x1 = expf(e1 - mx), x2 = expf(e2 - mx);
  float s = x0 + x1 + x2;
  wout[0*NH + h] = x0 / s; wout[1*NH + h] = x1 / s; wout[2*NH + h] = x2 / s;
}

// =====================================================================
// gated delta scan, v2. One wave per (e,b,h, 8-col chunk). ebh is the FAST
// block dim (same-ebh chunks land on the same XCD under the %8 heuristic ->
// L2-resident streams). Software-pipelined: k[t+1] + scalars prefetched
// unconditionally while computing t; q loaded just-in-time. All streams are
// pointer-incremented (offset-immediate loads, no per-t 64-bit address math).
// Producers pad each stream by one row so the t=Lc prefetch is in-bounds.
// =====================================================================
__global__ __launch_bounds__(64) void scan_kernel(
    const float* __restrict__ ke, const float* __restrict__ q,
    const ushort* __restrict__ v, const float* __restrict__ dec,
    const float* __restrict__ bm, const float* __restrict__ wout,
    float* __restrict__ o) {
  const int wg = blockIdx.x;
  const int ebh = wg % 48;
  const int chunk = wg / 48;            // 0..63
  const int e = ebh % 3;
  const int bh = ebh / 3;
  const int b = bh >> 3, h = bh & 7;
  const int lane = threadIdx.x;
  const int vl = lane & 7, p = lane >> 3;

  float S[32];
#pragma unroll
  for (int i = 0; i < 32; i++) S[i] = 0.f;

  const float* decp = dec + ((size_t)(e * Bc + b) * NH + h) * Lc;
  const float* bmp  = bm  + ((size_t)(e * Bc + b) * NH + h) * Lc;
  const float weh = wout[e * NH + h];
  const float* kptr = ke + ((size_t)e * BL + (size_t)b * Lc) * KD + h * HD + p * 32;
  const float* qptr = q  + ((size_t)b * Lc) * KD + h * HD + p * 32;
  const ushort* vptr = v + ((size_t)b * Lc) * VD + h * DV + chunk * 8 + vl;
  float* obt = o + (size_t)b * Lc * VD + h * DV + chunk * 8;

  float4 kr[8];
#pragma unroll
  for (int i = 0; i < 8; i++) kr[i] = *(const float4*)&kptr[i * 4];
  float dct = decp[0], bmt = bmp[0];
  float vv = bf2f(vptr[0]);

#pragma unroll 2
  for (int t = 0; t < Lc; t++) {
    // ---- prefetch t+1 (unconditional; padded at t=Lc-1) ----
    const float* knext = kptr + KD;
    float4 kn[8];
#pragma unroll
    for (int i = 0; i < 8; i++) kn[i] = *(const float4*)&knext[i * 4];
    float dn = decp[1];
    float bn = bmp[1];
    float vn = bf2f(vptr[VD]);
    // ---- q for current t (just-in-time; hidden behind dot+reduce) ----
    float4 qr[8];
#pragma unroll
    for (int i = 0; i < 8; i++) qr[i] = *(const float4*)&qptr[i * 4];

    float o0 = 0.f, o1 = 0.f, o2 = 0.f, o3 = 0.f;
    if (!(bmt == 0.f && dct == 1.f)) {
      float pr0 = 0.f, pr1 = 0.f, pr2 = 0.f, pr3 = 0.f;
#pragma unroll
      for (int i = 0; i < 8; i++) {
        pr0 = fmaf(kr[i].x, S[4*i+0], pr0);
        pr1 = fmaf(kr[i].y, S[4*i+1], pr1);
        pr2 = fmaf(kr[i].z, S[4*i+2], pr2);
        pr3 = fmaf(kr[i].w, S[4*i+3], pr3);
      }
      float part = (pr0 + pr1) + (pr2 + pr3);
      part += __shfl_xor(part, 8, 64);
      part += __shfl_xor(part, 16, 64);
      part += __shfl_xor(part, 32, 64);
      const float delta = (vv - dct * part) * bmt;
#pragma unroll
      for (int i = 0; i < 8; i++) {
        float s0 = fmaf(kr[i].x, delta, dct * S[4*i+0]); S[4*i+0] = s0; o0 = fmaf(qr[i].x, s0, o0);
        float s1 = fmaf(kr[i].y, delta, dct * S[4*i+1]); S[4*i+1] = s1; o1 = fmaf(qr[i].y, s1, o1);
        float s2 = fmaf(kr[i].z, delta, dct * S[4*i+2]); S[4*i+2] = s2; o2 = fmaf(qr[i].z, s2, o2);
        float s3 = fmaf(kr[i].w, delta, dct * S[4*i+3]); S[4*i+3] = s3; o3 = fmaf(qr[i].w, s3, o3);
      }
    } else {
#pragma unroll
      for (int i = 0; i < 8; i++) {
        o0 = fmaf(qr[i].x, S[4*i+0], o0);
        o1 = fmaf(qr[i].y, S[4*i+1], o1);
        o2 = fmaf(qr[i].z, S[4*i+2], o2);
        o3 = fmaf(qr[i].w, S[4*i+3], o3);
      }
    }
    float opart = (o0 + o1) + (o2 + o3);
    opart += __shfl_xor(opart, 8, 64);
    opart += __shfl_xor(opart, 16, 64);
    opart += __shfl_xor(opart, 32, 64);
    if (p == 0) atomicAdd(&obt[vl], weh * opart);

    // ---- rotate pipeline ----
#pragma unroll
    for (int i = 0; i < 8; i++) kr[i] = kn[i];
    dct = dn; bmt = bn; vv = vn;
    kptr = knext; qptr += KD; vptr += VD; obt += VD;
    decp++; bmp++;
  }
}

// =====================================================================
// RMSNorm(DV) * o_norm_weight * SiLU(gate). gate read (bf16) from xcat.
// =====================================================================
__global__ __launch_bounds__(256) void gate_kernel(float* __restrict__ o,
    const ushort* __restrict__ xg, int ldg, const float* __restrict__ onw) {
  int wid = threadIdx.x >> 6, lane = threadIdx.x & 63;
  int row = (blockIdx.x << 2) + wid;      // over BL*NH
  if (row >= BL * NH) return;
  int t = row >> 3, h = row & 7;
  float* op = o + (size_t)t * VD + h * DV;
  const ushort* gp = xg + (size_t)t * ldg + h * DV;
  float4 a0 = *(const float4*)&op[lane * 8];
  float4 a1 = *(const float4*)&op[lane * 8 + 4];
  float ss = a0.x*a0.x + a0.y*a0.y + a0.z*a0.z + a0.w*a0.w
           + a1.x*a1.x + a1.y*a1.y + a1.z*a1.z + a1.w*a1.w;
#pragma unroll
  for (int off = 32; off >= 1; off >>= 1) ss += __shfl_xor(ss, off, 64);
  float r = rsqrtf(ss * (1.f / DV) + 1e-5f);
  ushort4 gu0 = *(const ushort4*)&gp[lane * 8];
  ushort4 gu1 = *(const ushort4*)&gp[lane * 8 + 4];
  float4 n0 = *(const float4*)&onw[lane * 8];
  float4 n1 = *(const float4*)&onw[lane * 8 + 4];
  float g;
  g = bf2f(gu0.x); a0.x = a0.x * r * n0.x * (g * sigf(g));
  g = bf2f(gu0.y); a0.y = a0.y * r * n0.y * (g * sigf(g));
  g = bf2f(gu0.z); a0.z = a0.z * r * n0.z * (g * sigf(g));
  g = bf2f(gu0.w); a0.w = a0.w * r * n0.w * (g * sigf(g));
  g = bf2f(gu1.x); a1.x = a1.x * r * n1.x * (g * sigf(g));
  g = bf2f(gu1.y); a1.y = a1.y * r * n1.y * (g * sigf(g));
  g = bf2f(gu1.z); a1.z = a1.z * r * n1.z * (g * sigf(g));
  g = bf2f(gu1.w); a1.w = a1.w * r * n1.w * (g * sigf(g));
  *(float4*)&op[lane * 8]     = a0;
  *(float4*)&op[lane * 8 + 4] = a1;
}

// =====================================================================
extern "C" void kernel_launch(void* const* d_in, const int* in_sizes, int n_in,
                              void* d_out, int out_size, void* d_ws, size_t ws_size,
                              hipStream_t stream) {
  const float* x    = (const float*)d_in[0];
  const int*   modv = (const int*)d_in[1];
  const float* Wq   = (const float*)d_in[2];
  const float* Wk   = (const float*)d_in[3];
  const float* Wv   = (const float*)d_in[4];
  const float* cq   = (const float*)d_in[5];
  const float* ck   = (const float*)d_in[6];
  const float* cv   = (const float*)d_in[7];
  const float* Wek  = (const float*)d_in[8];
  const float* Wb   = (const float*)d_in[9];
  const float* Wa   = (const float*)d_in[10];
  const float* Alog = (const float*)d_in[11];
  const float* dtb  = (const float*)d_in[12];
  const float* ow   = (const float*)d_in[13];
  const float* Wg   = (const float*)d_in[14];
  const float* onw  = (const float*)d_in[15];
  const float* Wo   = (const float*)d_in[16];
  float* out = (float*)d_out;

  // ---- workspace layout (~197.5 MB; round-1 proved ws >= ~202 MB) ----
  char* base = (char*)d_ws;
  size_t off = 0;
  auto alloc = [&](size_t bytes) { char* p = base + off; off += (bytes + 255) & ~255ULL; return p; };

  ushort* xcat  = (ushort*)alloc((size_t)BL * NCAT * 2);          // 50.3 MB bf16 q|k|v|g proj
  char*   wkreg = alloc(((size_t)NE * BL + 1) * KD * 4);          // 50.3 MB+pad: Wcat bf16 -> keb f32
  ushort* wekbf = (ushort*)alloc((size_t)NE * NH * HD * HD * 2);  // 3.1 MB
  ushort* xbf   = (ushort*)alloc((size_t)BL * HS * 2);            // 8.4 MB -> kbbf
  float*  qb    = (float*) alloc(((size_t)BL + 1) * KD * 4);      // 16.8 MB+pad
  char*   kbreg = alloc((size_t)BL * KD * 4);                     // 16.8 MB: kb f32 -> wobf bf16
  char*   vreg  = alloc(((size_t)BL + 1) * VD * 2);               // 16.8 MB+pad: v bf16 -> obbf
  float*  ob    = (float*) alloc((size_t)BL * VD * 4);            // 33.6 MB
  float*  xba   = (float*) alloc((size_t)BL * 48 * 4);            // 393 KB
  float*  wba   = (float*) alloc((size_t)48 * HS * 4);            // 393 KB
  float*  decb  = (float*) alloc((size_t)NE * BL * NH * 4 + 1024);
  float*  bmb   = (float*) alloc((size_t)NE * BL * NH * 4 + 1024);
  float*  woutb = (float*) alloc(NE * NH * 4);

  ushort* Wcat = (ushort*)wkreg;          // phase A
  float*  keb  = (float*)wkreg;           // phase C/D (after gemm_big done)
  ushort* kbbf = xbf;                     // after gemm_big done
  float*  kb   = (float*)kbreg;           // phase B/C
  ushort* wobf = (ushort*)kbreg;          // after l2norm-k
  ushort* vbf  = (ushort*)vreg;           // phase B..D
  ushort* obbf = (ushort*)vreg;           // after scan

  dim3 blk(256);
  // ---- bf16 conversions (x + weights, fused) ----
  cvt_kernel<<<4096, blk, 0, stream>>>(x,  xbf, BL * HS / 4);
  cvt4_kernel<<<24576, blk, 0, stream>>>(Wq, Wk, Wv, Wg, Wcat);
  cvt_kernel<<<1536, blk, 0, stream>>>(Wek, wekbf, NE * NH * HD * HD / 4);
  // ---- Wb|Wa concat (d2d) ----
  hipMemcpyAsync(wba, Wb, (size_t)24 * HS * 4, hipMemcpyDeviceToDevice, stream);
  hipMemcpyAsync(wba + (size_t)24 * HS, Wa, (size_t)24 * HS * 4, hipMemcpyDeviceToDevice, stream);
  // ---- fused q|k|v|g projection (bf16 MFMA, bf16 out) ----
  gemm_big_kernel<<<dim3(NCAT/128, BL/128), blk, 0, stream>>>(xbf, Wcat, xcat);
  // ---- fused gate projection (fp32, N=48) ----
  gemm_nt_kernel<<<dim3(1, BL/64), blk, 0, stream>>>(x, wba, xba, BL, 48, HS);
  // ---- conv + silu (reads strided bf16 xcat) ----
  conv_silu_kernel<<<4096, blk, 0, stream>>>(xcat,        NCAT, cq, qb, KD, 0);
  conv_silu_kernel<<<4096, blk, 0, stream>>>(xcat + KD,   NCAT, ck, kb, KD, 0);
  conv_silu_kernel<<<8192, blk, 0, stream>>>(xcat + 2*KD, NCAT, cv, vbf, VD, 1);
  // ---- l2norm: q f32 in-place (*HD^-0.5), k -> bf16 directly ----
  l2norm_kernel<<<(BL*NH)/4, blk, 0, stream>>>(qb, qb, 0.0625f, BL*NH, 0);
  l2norm_kernel<<<(BL*NH)/4, blk, 0, stream>>>(kb, kbbf, 1.0f,  BL*NH, 1);
  // ---- Wo -> bf16 into kb's (now dead) region ----
  cvt_kernel<<<8192, blk, 0, stream>>>(Wo, wobf, HS * VD / 4);
  // ---- per-expert per-head key transform (bf16 MFMA, f32 out) ----
  gemm_ke_kernel<<<dim3(HD/128, BL/128, NE*NH), blk, 0, stream>>>(kbbf, wekbf, keb);
  // ---- gate scalars + expert mixing ----
  scalars_kernel<<<(BL*NE*NH + 255)/256, blk, 0, stream>>>(xba, modv, Alog, dtb, decb, bmb);
  wout_kernel<<<1, 64, 0, stream>>>(ow, woutb);
  // ---- scan ----
  hipMemsetAsync(ob, 0, (size_t)BL * VD * sizeof(float), stream);
  scan_kernel<<<NE * Bc * NH * 64, 64, 0, stream>>>(keb, qb, vbf, decb, bmb, woutb, ob);
  // ---- RMSNorm * silu(gate) ----
  gate_kernel<<<(BL*NH)/4, blk, 0, stream>>>(ob, xcat + 2*KD + VD, NCAT, onw);
  // ---- output projection (bf16 MFMA) ----
  cvt_kernel<<<8192, blk, 0, stream>>>(ob, obbf, BL * VD / 4);
  gemm_wo_kernel<<<dim3(HS/128, BL/128), blk, 0, stream>>>(obbf, wobf, out);
}

// Round 5
// 1031.008 us; speedup vs baseline: 2.1533x; 2.1533x over previous
//
#include <hip/hip_runtime.h>
#include <math.h>

// ---- problem constants ----
constexpr int Bc  = 2;
constexpr int Lc  = 1024;
constexpr int BL  = Bc * Lc;    // 2048
constexpr int HS  = 2048;
constexpr int NH  = 8;
constexpr int HD  = 256;
constexpr int DV  = 512;
constexpr int KD  = NH * HD;    // 2048
constexpr int VD  = NH * DV;    // 4096
constexpr int NE  = 3;
constexpr int KSZ = 4;
constexpr int NCAT = 12288;     // Wq|Wk|Wv|Wg rows concatenated
constexpr int NEBH = 48;        // NE*Bc*NH
constexpr int NCHUNK = 16;      // Lc/64

__device__ __forceinline__ float sigf(float x) { return 1.f / (1.f + expf(-x)); }

__device__ __forceinline__ ushort f2bf(float f) {
  unsigned u = __float_as_uint(f);
  unsigned r = u + 0x7fffu + ((u >> 16) & 1u);
  return (ushort)(r >> 16);
}
__device__ __forceinline__ float bf2f(ushort u) {
  return __uint_as_float(((unsigned)u) << 16);
}

typedef __attribute__((ext_vector_type(8))) short bf16x8;
typedef __attribute__((ext_vector_type(4))) float f32x4;

#define AS1C(p) ((const __attribute__((address_space(1))) void*)(p))
#define AS3(p)  ((__attribute__((address_space(3))) void*)(p))
#define MFMA(a,b,c) __builtin_amdgcn_mfma_f32_16x16x32_bf16((a),(b),(c),0,0,0)

// =====================================================================
// fp32 -> bf16 (RNE) elementwise, vectorized x4
// =====================================================================
__global__ __launch_bounds__(256) void cvt_kernel(const float* __restrict__ in,
                                                  ushort* __restrict__ out, int n4) {
  int i = blockIdx.x * blockDim.x + threadIdx.x;
  if (i >= n4) return;
  float4 v = ((const float4*)in)[i];
  ushort4 o;
  o.x = f2bf(v.x); o.y = f2bf(v.y); o.z = f2bf(v.z); o.w = f2bf(v.w);
  ((ushort4*)out)[i] = o;
}

// fused 4-source weight conversion into contiguous Wcat (Wq|Wk|Wv|Wg)
__global__ __launch_bounds__(256) void cvt4_kernel(const float* __restrict__ wq,
    const float* __restrict__ wk, const float* __restrict__ wv,
    const float* __restrict__ wg, ushort* __restrict__ out) {
  const int s0 = KD * HS / 4, s1 = 2 * s0, s2 = s1 + VD * HS / 4, s3 = s2 + VD * HS / 4;
  int i = blockIdx.x * blockDim.x + threadIdx.x;
  if (i >= s3) return;
  const float* src; int j;
  if (i < s0)      { src = wq; j = i; }
  else if (i < s1) { src = wk; j = i - s0; }
  else if (i < s2) { src = wv; j = i - s1; }
  else             { src = wg; j = i - s2; }
  float4 v = ((const float4*)src)[j];
  ushort4 o;
  o.x = f2bf(v.x); o.y = f2bf(v.y); o.z = f2bf(v.z); o.w = f2bf(v.w);
  ((ushort4*)out)[i] = o;
}

// =====================================================================
// bf16 MFMA GEMM core (m97 structure), 128x128 tile, BK=32, 4 waves.
// =====================================================================
template<bool BF16OUT>
__device__ __forceinline__ void mfma_core(const ushort* __restrict__ A, int lda,
                                          const ushort* __restrict__ B, int ldb,
                                          void* __restrict__ Cv, int ldc,
                                          int K, int m0, int n0,
                                          ushort* As, ushort* Bs) {
  const int tid = threadIdx.x;
  const int w = tid >> 6, lane = tid & 63;
  const int wm = (w >> 1) << 6, wn = (w & 1) << 6;
  f32x4 acc[4][4];
#pragma unroll
  for (int i = 0; i < 4; i++)
#pragma unroll
    for (int j = 0; j < 4; j++) acc[i][j] = (f32x4){0.f, 0.f, 0.f, 0.f};

  const int rc = lane >> 2;
  const int slot = lane & 3;
  const int r0 = (2 * w) * 16 + rc;
  const int r1 = (2 * w + 1) * 16 + rc;
  const int g0 = slot ^ (r0 & 3);
  const int g1 = slot ^ (r1 & 3);
  const ushort* A0 = A + (size_t)(m0 + r0) * lda + g0 * 8;
  const ushort* A1 = A + (size_t)(m0 + r1) * lda + g1 * 8;
  const ushort* B0 = B + (size_t)(n0 + r0) * ldb + g0 * 8;
  const ushort* B1 = B + (size_t)(n0 + r1) * ldb + g1 * 8;
  ushort* lA0 = As + (2 * w) * 512;
  ushort* lA1 = As + (2 * w + 1) * 512;
  ushort* lB0 = Bs + (2 * w) * 512;
  ushort* lB1 = Bs + (2 * w + 1) * 512;

  const int gi = ((lane >> 4) ^ (lane & 3)) << 3;
  const int fr = lane & 15;

  for (int k0 = 0; k0 < K; k0 += 32) {
    __builtin_amdgcn_global_load_lds(AS1C(A0 + k0), AS3(lA0), 16, 0, 0);
    __builtin_amdgcn_global_load_lds(AS1C(A1 + k0), AS3(lA1), 16, 0, 0);
    __builtin_amdgcn_global_load_lds(AS1C(B0 + k0), AS3(lB0), 16, 0, 0);
    __builtin_amdgcn_global_load_lds(AS1C(B1 + k0), AS3(lB1), 16, 0, 0);
    __syncthreads();
    bf16x8 af[4], bff[4];
#pragma unroll
    for (int i = 0; i < 4; i++) {
      af[i]  = *(const bf16x8*)&As[(wm + i * 16 + fr) * 32 + gi];
      bff[i] = *(const bf16x8*)&Bs[(wn + i * 16 + fr) * 32 + gi];
    }
#pragma unroll
    for (int i = 0; i < 4; i++)
#pragma unroll
      for (int j = 0; j < 4; j++)
        acc[i][j] = MFMA(af[i], bff[j], acc[i][j]);
    __syncthreads();
  }
#pragma unroll
  for (int i = 0; i < 4; i++) {
#pragma unroll
    for (int r = 0; r < 4; r++) {
      int row = m0 + wm + i * 16 + (lane >> 4) * 4 + r;
#pragma unroll
      for (int j = 0; j < 4; j++) {
        int col = n0 + wn + j * 16 + fr;
        float val = acc[i][j][r];
        if (BF16OUT) ((ushort*)Cv)[(size_t)row * ldc + col] = f2bf(val);
        else         ((float*)Cv)[(size_t)row * ldc + col]  = val;
      }
    }
  }
}

// fused q|k|v|g projection, outputs routed to 4 separate bf16 buffers
__global__ __launch_bounds__(256) void gemm_big_kernel(const ushort* __restrict__ A,
    const ushort* __restrict__ B, ushort* __restrict__ xq, ushort* __restrict__ xk,
    ushort* __restrict__ xv, ushort* __restrict__ xg) {
  __shared__ ushort As[4096], Bs[4096];
  int nb = blockIdx.x;
  ushort* Cb; int ldc; int coff;
  if (nb < 16)      { Cb = xq; ldc = KD; coff = 0; }
  else if (nb < 32) { Cb = xk; ldc = KD; coff = 2048; }
  else if (nb < 64) { Cb = xv; ldc = VD; coff = 4096; }
  else              { Cb = xg; ldc = VD; coff = 8192; }
  mfma_core<true>(A, HS, B, HS, Cb - coff, ldc, HS, blockIdx.y * 128, nb * 128, As, Bs);
}

__global__ __launch_bounds__(256) void gemm_wo_kernel(const ushort* __restrict__ A,
    const ushort* __restrict__ B, float* __restrict__ C) {
  __shared__ ushort As[4096], Bs[4096];
  mfma_core<false>(A, VD, B, VD, C, HS, VD, blockIdx.y * 128, blockIdx.x * 128, As, Bs);
}

// ke[e, t, h*HD + c] = sum_d kbf[t, h*HD+d] * wek[e,h,c,d]; bf16 output
__global__ __launch_bounds__(256) void gemm_ke_kernel(const ushort* __restrict__ kbf,
    const ushort* __restrict__ wek, ushort* __restrict__ ke) {
  __shared__ ushort As[4096], Bs[4096];
  int z = blockIdx.z, e = z >> 3, h = z & 7;
  mfma_core<true>(kbf + h * HD, KD, wek + (size_t)z * HD * HD, HD,
                  ke + (size_t)e * BL * KD + h * HD, KD, HD,
                  blockIdx.y * 128, blockIdx.x * 128, As, Bs);
}

// =====================================================================
// fp32 GEMM (small N: fused Wb|Wa projection), 64x64 tile
// =====================================================================
__global__ __launch_bounds__(256) void gemm_nt_kernel(const float* __restrict__ A,
    const float* __restrict__ W, float* __restrict__ C, int M, int N, int K) {
  __shared__ float As[16*68];
  __shared__ float Ws[16*68];
  const int tid = threadIdx.x;
  const int m0 = blockIdx.y * 64, n0 = blockIdx.x * 64;
  const int tx = tid & 15, ty = tid >> 4;
  const int lr = tid >> 2;
  const int lc = (tid & 3) << 2;
  float acc[4][4] = {{0.f,0.f,0.f,0.f},{0.f,0.f,0.f,0.f},{0.f,0.f,0.f,0.f},{0.f,0.f,0.f,0.f}};
  for (int k0 = 0; k0 < K; k0 += 16) {
    float4 av = make_float4(0.f,0.f,0.f,0.f), wv = make_float4(0.f,0.f,0.f,0.f);
    if (m0 + lr < M) av = *(const float4*)&A[(size_t)(m0 + lr) * K + k0 + lc];
    if (n0 + lr < N) wv = *(const float4*)&W[(size_t)(n0 + lr) * K + k0 + lc];
    __syncthreads();
    As[(lc+0)*68 + lr] = av.x; As[(lc+1)*68 + lr] = av.y;
    As[(lc+2)*68 + lr] = av.z; As[(lc+3)*68 + lr] = av.w;
    Ws[(lc+0)*68 + lr] = wv.x; Ws[(lc+1)*68 + lr] = wv.y;
    Ws[(lc+2)*68 + lr] = wv.z; Ws[(lc+3)*68 + lr] = wv.w;
    __syncthreads();
#pragma unroll
    for (int kk = 0; kk < 16; kk++) {
      float4 a4 = *(const float4*)&As[kk*68 + ty*4];
      float4 w4 = *(const float4*)&Ws[kk*68 + tx*4];
      float ar[4] = {a4.x, a4.y, a4.z, a4.w};
      float wr[4] = {w4.x, w4.y, w4.z, w4.w};
#pragma unroll
      for (int i = 0; i < 4; i++)
#pragma unroll
        for (int j = 0; j < 4; j++)
          acc[i][j] = fmaf(ar[i], wr[j], acc[i][j]);
    }
  }
#pragma unroll
  for (int i = 0; i < 4; i++) {
    int m = m0 + ty*4 + i;
    if (m >= M) continue;
#pragma unroll
    for (int j = 0; j < 4; j++) {
      int n = n0 + tx*4 + j;
      if (n < N) C[(size_t)m * N + n] = acc[i][j];
    }
  }
}

// =====================================================================
// causal depthwise conv (K=4) + SiLU. x: bf16 [BL, C]. y f32 or bf16.
// =====================================================================
__global__ __launch_bounds__(256) void conv_silu_kernel(const ushort* __restrict__ x,
    const float* __restrict__ w, void* __restrict__ y, int C, int obf) {
  int idx = blockIdx.x * blockDim.x + threadIdx.x;
  int nc4 = C >> 2;
  if (idx >= BL * nc4) return;
  int c4 = (idx % nc4) << 2;
  int t  = idx / nc4;
  int l = t & (Lc - 1);
  float4 w0 = *(const float4*)&w[(c4+0)*KSZ];
  float4 w1 = *(const float4*)&w[(c4+1)*KSZ];
  float4 w2 = *(const float4*)&w[(c4+2)*KSZ];
  float4 w3 = *(const float4*)&w[(c4+3)*KSZ];
  const float* p0 = (const float*)&w0; const float* p1 = (const float*)&w1;
  const float* p2 = (const float*)&w2; const float* p3 = (const float*)&w3;
  float4 acc = make_float4(0.f,0.f,0.f,0.f);
#pragma unroll
  for (int i = 0; i < KSZ; i++) {
    int ls = l - (KSZ - 1) + i;
    if (ls < 0) continue;
    ushort4 xu = *(const ushort4*)&x[(size_t)(t - (KSZ - 1) + i) * C + c4];
    acc.x = fmaf(bf2f(xu.x), p0[i], acc.x);
    acc.y = fmaf(bf2f(xu.y), p1[i], acc.y);
    acc.z = fmaf(bf2f(xu.z), p2[i], acc.z);
    acc.w = fmaf(bf2f(xu.w), p3[i], acc.w);
  }
  acc.x *= sigf(acc.x); acc.y *= sigf(acc.y); acc.z *= sigf(acc.z); acc.w *= sigf(acc.w);
  if (obf) {
    ushort4 o;
    o.x = f2bf(acc.x); o.y = f2bf(acc.y); o.z = f2bf(acc.z); o.w = f2bf(acc.w);
    *(ushort4*)&((ushort*)y)[(size_t)t * C + c4] = o;
  } else {
    *(float4*)&((float*)y)[(size_t)t * C + c4] = acc;
  }
}

// =====================================================================
// fused conv(K=4)+SiLU+transpose for v: xv[BL,VD] bf16 -> v_T[VD,BL] bf16
// =====================================================================
__global__ __launch_bounds__(256) void conv_v_t_kernel(const ushort* __restrict__ xv,
    const float* __restrict__ wv, ushort* __restrict__ v_T) {
  __shared__ ushort tile[64 * 68];
  const int cb = blockIdx.x * 64, tb = blockIdx.y * 64;
  const int tid = threadIdx.x;
  const int cl4 = (tid & 15) * 4;
  const int c = cb + cl4;
  float4 w0 = *(const float4*)&wv[(c+0)*KSZ];
  float4 w1 = *(const float4*)&wv[(c+1)*KSZ];
  float4 w2 = *(const float4*)&wv[(c+2)*KSZ];
  float4 w3 = *(const float4*)&wv[(c+3)*KSZ];
  const float* p0 = (const float*)&w0; const float* p1 = (const float*)&w1;
  const float* p2 = (const float*)&w2; const float* p3 = (const float*)&w3;
#pragma unroll
  for (int p = 0; p < 4; p++) {
    int tr = p * 16 + (tid >> 4);
    int t = tb + tr;
    int l = t & (Lc - 1);
    float acc[4] = {0.f, 0.f, 0.f, 0.f};
#pragma unroll
    for (int i = 0; i < KSZ; i++) {
      int ls = l - (KSZ - 1) + i;
      if (ls < 0) continue;
      ushort4 xu = *(const ushort4*)&xv[(size_t)(t - (KSZ - 1) + i) * VD + c];
      acc[0] = fmaf(bf2f(xu.x), p0[i], acc[0]);
      acc[1] = fmaf(bf2f(xu.y), p1[i], acc[1]);
      acc[2] = fmaf(bf2f(xu.z), p2[i], acc[2]);
      acc[3] = fmaf(bf2f(xu.w), p3[i], acc[3]);
    }
#pragma unroll
    for (int u = 0; u < 4; u++) {
      float s = acc[u] * sigf(acc[u]);
      tile[(cl4 + u) * 68 + tr] = f2bf(s);
    }
  }
  __syncthreads();
#pragma unroll
  for (int s = 0; s < 16; s++) {
    int idx = s * 256 + tid;
    int cl = idx >> 6, tl = idx & 63;
    v_T[(size_t)(cb + cl) * BL + tb + tl] = tile[cl * 68 + tl];
  }
}

// =====================================================================
// l2norm over last dim (HD=256), one wave per row; out f32 or bf16
// =====================================================================
__global__ __launch_bounds__(256) void l2norm_kernel(const float* __restrict__ in,
    void* __restrict__ outp, float scale, int rows, int obf) {
  int wid = threadIdx.x >> 6, lane = threadIdx.x & 63;
  int row = (blockIdx.x << 2) + wid;
  if (row >= rows) return;
  const float* p = in + (size_t)row * HD;
  float4 a = *(const float4*)&p[lane * 4];
  float ss = a.x*a.x + a.y*a.y + a.z*a.z + a.w*a.w;
#pragma unroll
  for (int off = 32; off >= 1; off >>= 1) ss += __shfl_xor(ss, off, 64);
  float r = rsqrtf(ss + 1e-6f) * scale;
  a.x *= r; a.y *= r; a.z *= r; a.w *= r;
  if (obf) {
    ushort4 o;
    o.x = f2bf(a.x); o.y = f2bf(a.y); o.z = f2bf(a.z); o.w = f2bf(a.w);
    *(ushort4*)&((ushort*)outp)[(size_t)row * HD + lane * 4] = o;
  } else {
    *(float4*)&((float*)outp)[(size_t)row * HD + lane * 4] = a;
  }
}

// =====================================================================
// per-token gate scalars: logdec = m*g, bm = beta*m
// =====================================================================
__global__ __launch_bounds__(256) void scalars_kernel(const float* __restrict__ xba,
    const int* __restrict__ modality,
    const float* __restrict__ A_log, const float* __restrict__ dt_bias,
    float* __restrict__ logdec, float* __restrict__ bm) {
  int idx = blockIdx.x * blockDim.x + threadIdx.x;
  if (idx >= BL * NE * NH) return;
  int eh = idx % (NE * NH);
  int t  = idx / (NE * NH);
  int e = eh / NH, h = eh % NH;
  float a    = xba[(size_t)t * 48 + 24 + eh];
  float beta = sigf(xba[(size_t)t * 48 + eh]);
  int md = modality[t];
  float m = (e == 0) ? 1.f : ((e == 1) ? (md == 0 ? 1.f : 0.f) : (md == 1 ? 1.f : 0.f));
  float spin = a + dt_bias[eh];
  float sp = (spin > 20.f) ? spin : log1pf(expf(spin));
  float g = -expf(A_log[eh]) * sp;
  int b = t / Lc, l = t % Lc;
  size_t off = ((size_t)(e * Bc + b) * NH + h) * Lc + l;
  logdec[off] = m * g;
  bm[off]  = beta * m;
}

__global__ void wout_kernel(const float* __restrict__ ow, float* __restrict__ wout) {
  int h = threadIdx.x;
  if (h >= NH) return;
  float e0 = ow[0*NH + h], e1 = ow[1*NH + h], e2 = ow[2*NH + h];
  float mx = fmaxf(e0, fmaxf(e1, e2));
  float x0 = expf(e0 - mx), x1 = expf(e1 - mx), x2 = expf(e2 - mx);
  float s = x0 + x1 + x2;
  wout[0*NH + h] = x0 / s; wout[1*NH + h] = x1 / s; wout[2*NH + h] = x2 / s;
}

// =====================================================================
// prep: per (ebh,chunk): T=(I+B)^-1, P (decayed QK^T), scale vectors.
// block z = ebh*16 + c, 256 threads (4 waves).
// =====================================================================
__global__ __launch_bounds__(256) void prep_kernel(
    const ushort* __restrict__ kebf, const ushort* __restrict__ qbf,
    const float* __restrict__ logdecb, const float* __restrict__ bmb,
    ushort* __restrict__ Tb, ushort* __restrict__ Pb,
    float* __restrict__ slamb, float* __restrict__ kscb) {
  const int z = blockIdx.x;
  const int ebh = z >> 4, c = z & 15;
  const int e = ebh >> 4, b = (ebh >> 3) & 1, h = ebh & 7;
  const int tid = threadIdx.x, w = tid >> 6, lane = tid & 63;
  const int fr = lane & 15, fg = lane >> 4;
  __shared__ float Bm[64 * 65];
  __shared__ float Tt[64 * 65];     // Tt[col][row] = T[row][col]
  __shared__ float Lsh[64], bmsh[64];

  const int t0 = c * 64;
  const ushort* keB = kebf + ((size_t)e * BL + (size_t)b * Lc + t0) * KD + h * HD;
  const ushort* qB  = qbf + ((size_t)b * Lc + t0) * KD + h * HD;

  // wave0: inclusive prefix scan of logdec, store exp(L), ksc
  if (w == 0) {
    float v = logdecb[(size_t)ebh * Lc + t0 + lane];
    for (int off = 1; off < 64; off <<= 1) {
      float n = __shfl_up(v, off, 64);
      if (lane >= off) v += n;
    }
    Lsh[lane] = v;
    bmsh[lane] = bmb[(size_t)ebh * Lc + t0 + lane];
    slamb[(size_t)ebh * Lc + t0 + lane] = expf(v);
    float l63 = __shfl(v, 63, 64);
    kscb[(size_t)z * 64 + lane] = expf(l63 - v);
  }
  __syncthreads();

  // G_kk: M_kk = ke ke^T, then B matrix (strict lower, scaled)
  {
    f32x4 kacc[4];
#pragma unroll
    for (int i = 0; i < 4; i++) kacc[i] = (f32x4){0.f,0.f,0.f,0.f};
    const ushort* Ar = &keB[(size_t)(w * 16 + fr) * KD];
    for (int kk = 0; kk < 8; kk++) {
      bf16x8 af = *(const bf16x8*)&Ar[kk * 32 + fg * 8];
#pragma unroll
      for (int nt = 0; nt < 4; nt++) {
        bf16x8 bf_ = *(const bf16x8*)&keB[(size_t)(nt * 16 + fr) * KD + kk * 32 + fg * 8];
        kacc[nt] = MFMA(af, bf_, kacc[nt]);
      }
    }
#pragma unroll
    for (int nt = 0; nt < 4; nt++)
#pragma unroll
      for (int r = 0; r < 4; r++) {
        int i = w * 16 + 4 * fg + r;
        int j = nt * 16 + fr;
        float val = (j < i) ? bmsh[i] * expf(Lsh[i] - Lsh[j]) * kacc[nt][r] : 0.f;
        Bm[i * 65 + j] = val;
      }
  }
  __syncthreads();

  // inversion (wave0, lane = column)
  if (w == 0) {
    Tt[lane * 65 + 0] = (lane == 0) ? 1.f : 0.f;
    for (int i = 1; i < 64; i++) {
      float a0 = 0.f, a1 = 0.f;
      int j = 0;
      for (; j + 1 < i; j += 2) {
        a0 = fmaf(Bm[i*65+j],   Tt[lane*65 + j],   a0);
        a1 = fmaf(Bm[i*65+j+1], Tt[lane*65 + j+1], a1);
      }
      if (j < i) a0 = fmaf(Bm[i*65+j], Tt[lane*65 + j], a0);
      Tt[lane * 65 + i] = ((lane == i) ? 1.f : 0.f) - (a0 + a1);
    }
  }
  __syncthreads();

  // write Tb bf16
  for (int idx = tid; idx < 4096; idx += 256) {
    int i = idx >> 6, j = idx & 63;
    Tb[(size_t)z * 4096 + idx] = f2bf(Tt[j * 65 + i]);
  }

  // G_qk: P = decayed-masked QK^T (incl diag)
  {
    f32x4 qacc[4];
#pragma unroll
    for (int i = 0; i < 4; i++) qacc[i] = (f32x4){0.f,0.f,0.f,0.f};
    const ushort* Ar = &qB[(size_t)(w * 16 + fr) * KD];
    for (int kk = 0; kk < 8; kk++) {
      bf16x8 af = *(const bf16x8*)&Ar[kk * 32 + fg * 8];
#pragma unroll
      for (int nt = 0; nt < 4; nt++) {
        bf16x8 bf_ = *(const bf16x8*)&keB[(size_t)(nt * 16 + fr) * KD + kk * 32 + fg * 8];
        qacc[nt] = MFMA(af, bf_, qacc[nt]);
      }
    }
#pragma unroll
    for (int nt = 0; nt < 4; nt++)
#pragma unroll
      for (int r = 0; r < 4; r++) {
        int i = w * 16 + 4 * fg + r;
        int j = nt * 16 + fr;
        float val = (j <= i) ? expf(Lsh[i] - Lsh[j]) * qacc[nt][r] : 0.f;
        Bm[i * 65 + j] = val;
      }
  }
  __syncthreads();
  for (int idx = tid; idx < 4096; idx += 256) {
    int i = idx >> 6, j = idx & 63;
    Pb[(size_t)z * 4096 + idx] = f2bf(Bm[i * 65 + j]);
  }
}

// =====================================================================
// kbar: K̄^T[z][hd][j] = exp(L63-Lj) * ke[j][hd]  (transposed, scaled, bf16)
// =====================================================================
__global__ __launch_bounds__(256) void kbar_kernel(const ushort* __restrict__ kebf,
    const float* __restrict__ kscb, ushort* __restrict__ KbarT) {
  const int z = blockIdx.x;
  const int ebh = z >> 4, c = z & 15;
  const int e = ebh >> 4, b = (ebh >> 3) & 1, h = ebh & 7;
  __shared__ ushort tile[256 * 66];
  __shared__ float ksc[64];
  const int tid = threadIdx.x;
  const ushort* keB = kebf + ((size_t)e * BL + (size_t)b * Lc + c * 64) * KD + h * HD;
  if (tid < 64) ksc[tid] = kscb[(size_t)z * 64 + tid];
  const int j = tid & 63, hblk = tid >> 6;
#pragma unroll
  for (int s = 0; s < 8; s++) {
    int hd0 = hblk * 64 + s * 8;
    const ushort* src = &keB[(size_t)j * KD + hd0];
    ushort4 u0 = *(const ushort4*)src;
    ushort4 u1 = *(const ushort4*)(src + 4);
    tile[(hd0+0)*66 + j] = u0.x; tile[(hd0+1)*66 + j] = u0.y;
    tile[(hd0+2)*66 + j] = u0.z; tile[(hd0+3)*66 + j] = u0.w;
    tile[(hd0+4)*66 + j] = u1.x; tile[(hd0+5)*66 + j] = u1.y;
    tile[(hd0+6)*66 + j] = u1.z; tile[(hd0+7)*66 + j] = u1.w;
  }
  __syncthreads();
  for (int idx = tid; idx < 16384; idx += 256) {
    int hd = idx >> 6, jj = idx & 63;
    KbarT[(size_t)z * 16384 + idx] = f2bf(bf2f(tile[hd * 66 + jj]) * ksc[jj]);
  }
}

// =====================================================================
// chunked MFMA scan. block = (ebh 48) x (dv-slice 4 of 128). 8 waves.
// S kept in LDS as bf16 hi+lo (Dekker split ~ fp32). 16 sequential chunks:
//   G1: [ke;q](128x256) x S(256x128)  -> rhs_T (LDS), oq (regs)
//   G2: Delta = T(64x64) x rhs        -> Delta_T (LDS)
//   G3 (waves 4-7): O = oq + P*Delta  -> weighted atomicAdd
//   G4 (waves 0-3): S = l63*S + Delta_T * KbarT
// =====================================================================
__global__ __launch_bounds__(512) void scan_mfma_kernel(
    const ushort* __restrict__ kebf, const ushort* __restrict__ qbf,
    const ushort* __restrict__ v_T,  const ushort* __restrict__ Tb,
    const ushort* __restrict__ Pb,   const ushort* __restrict__ KbarT,
    const float* __restrict__ bmb,   const float* __restrict__ slamb,
    const float* __restrict__ wout,  float* __restrict__ ob) {
  extern __shared__ char smem[];
  ushort* Shi = (ushort*)smem;               // 128*264
  ushort* Slo = Shi + 128 * 264;             // 128*264
  ushort* stg = Slo + 128 * 264;             // 128*68 (rhs_T then Delta_T)
  float* bmL = (float*)(stg + 128 * 68);
  float* slL = bmL + 64;

  const int bid = blockIdx.x;
  const int ebh = bid % NEBH;
  const int dvs = bid / NEBH;
  const int e = ebh >> 4, b = (ebh >> 3) & 1, h = ebh & 7;
  const int tid = threadIdx.x;
  const int w = tid >> 6, lane = tid & 63;
  const int fr = lane & 15, fg = lane >> 4;

  for (int i = tid; i < 128 * 264; i += 512) { Shi[i] = 0; Slo[i] = 0; }

  const float weh = wout[e * NH + h];
  const size_t tbase = (size_t)b * Lc;
  const ushort* keB = kebf + ((size_t)e * BL + tbase) * KD + h * HD;
  const ushort* qB  = qbf + tbase * KD + h * HD;
  const ushort* vB  = v_T + ((size_t)(h * DV + dvs * 128)) * BL + tbase;
  const float* bmG = bmb + (size_t)ebh * Lc;
  const float* slG = slamb + (size_t)ebh * Lc;
  const ushort* TbB = Tb + (size_t)ebh * 16 * 4096;
  const ushort* PbB = Pb + (size_t)ebh * 16 * 4096;
  const ushort* KtB = KbarT + (size_t)ebh * 16 * 16384;
  float* obB = ob + tbase * VD + h * DV + dvs * 128;

  for (int c = 0; c < NCHUNK; c++) {
    const int t0 = c * 64;
    if (tid < 64) { bmL[tid] = bmG[t0 + tid]; slL[tid] = slG[t0 + tid]; }
    __syncthreads();  // bar0: S + scalars ready

    // ---- G1 ----
    f32x4 acc[8];
#pragma unroll
    for (int i = 0; i < 8; i++) acc[i] = (f32x4){0.f,0.f,0.f,0.f};
    {
      int i_loc = (w & 3) * 16 + fr;
      const ushort* src = (w < 4) ? &keB[(size_t)(t0 + i_loc) * KD]
                                  : &qB[(size_t)(t0 + i_loc) * KD];
      for (int kk = 0; kk < 8; kk++) {
        bf16x8 af = *(const bf16x8*)&src[kk * 32 + fg * 8];
#pragma unroll
        for (int nt = 0; nt < 8; nt++) {
          int saddr = (nt * 16 + fr) * 264 + kk * 32 + fg * 8;
          bf16x8 bh_ = *(const bf16x8*)&Shi[saddr];
          bf16x8 bl_ = *(const bf16x8*)&Slo[saddr];
          acc[nt] = MFMA(af, bh_, acc[nt]);
          acc[nt] = MFMA(af, bl_, acc[nt]);
        }
      }
    }
    f32x4 oq[8];
    if (w < 4) {
      // rhs_T[n][i] = bm_i * (v - sl_i * Y)
      int ibase = (w & 3) * 16 + 4 * fg;
#pragma unroll
      for (int nt = 0; nt < 8; nt++) {
        int n = nt * 16 + fr;
        ushort4 vv = *(const ushort4*)&vB[(size_t)n * BL + t0 + ibase];
        ushort4 st;
        st.x = f2bf(bmL[ibase+0] * (bf2f(vv.x) - slL[ibase+0] * acc[nt][0]));
        st.y = f2bf(bmL[ibase+1] * (bf2f(vv.y) - slL[ibase+1] * acc[nt][1]));
        st.z = f2bf(bmL[ibase+2] * (bf2f(vv.z) - slL[ibase+2] * acc[nt][2]));
        st.w = f2bf(bmL[ibase+3] * (bf2f(vv.w) - slL[ibase+3] * acc[nt][3]));
        *(ushort4*)&stg[n * 68 + ibase] = st;
      }
    } else {
      int ibase = (w & 3) * 16 + 4 * fg;
#pragma unroll
      for (int nt = 0; nt < 8; nt++)
#pragma unroll
        for (int r = 0; r < 4; r++) oq[nt][r] = slL[ibase + r] * acc[nt][r];
    }
    __syncthreads();  // bar1: rhs_T ready

    // ---- G2: Delta = T x rhs ----
    f32x4 dacc[4];
#pragma unroll
    for (int i = 0; i < 4; i++) dacc[i] = (f32x4){0.f,0.f,0.f,0.f};
    {
      const int mt = w & 3, nb0 = (w >> 2) * 4;
      const ushort* Tc = TbB + (size_t)c * 4096;
      for (int kk = 0; kk < 2; kk++) {
        bf16x8 af = *(const bf16x8*)&Tc[(size_t)(mt * 16 + fr) * 64 + kk * 32 + fg * 8];
#pragma unroll
        for (int nn = 0; nn < 4; nn++) {
          bf16x8 bf_ = *(const bf16x8*)&stg[((nb0 + nn) * 16 + fr) * 68 + kk * 32 + fg * 8];
          dacc[nn] = MFMA(af, bf_, dacc[nn]);
        }
      }
    }
    __syncthreads();  // bar2: all rhs reads done
    {
      const int mt = w & 3, nb0 = (w >> 2) * 4;
      int ibase = mt * 16 + 4 * fg;
#pragma unroll
      for (int nn = 0; nn < 4; nn++) {
        int n = (nb0 + nn) * 16 + fr;
        ushort4 st;
        st.x = f2bf(dacc[nn][0]); st.y = f2bf(dacc[nn][1]);
        st.z = f2bf(dacc[nn][2]); st.w = f2bf(dacc[nn][3]);
        *(ushort4*)&stg[n * 68 + ibase] = st;
      }
    }
    __syncthreads();  // bar3: Delta_T ready

    if (w >= 4) {
      // ---- G3: O = oq + P*Delta, then atomic write ----
      const int mt = w - 4;
      const ushort* Pc = PbB + (size_t)c * 4096;
      for (int kk = 0; kk < 2; kk++) {
        bf16x8 af = *(const bf16x8*)&Pc[(size_t)(mt * 16 + fr) * 64 + kk * 32 + fg * 8];
#pragma unroll
        for (int nt = 0; nt < 8; nt++) {
          bf16x8 bf_ = *(const bf16x8*)&stg[(nt * 16 + fr) * 68 + kk * 32 + fg * 8];
          oq[nt] = MFMA(af, bf_, oq[nt]);
        }
      }
#pragma unroll
      for (int nt = 0; nt < 8; nt++) {
        int n = nt * 16 + fr;
#pragma unroll
        for (int r = 0; r < 4; r++) {
          int i = mt * 16 + 4 * fg + r;
          atomicAdd(&obB[(size_t)(t0 + i) * VD + n], weh * oq[nt][r]);
        }
      }
    } else {
      // ---- G4: S = l63*S + Delta_T x KbarT ----
      const ushort* Kc = KtB + (size_t)c * 16384;
      const float l63 = slL[63];
      for (int half = 0; half < 2; half++) {
        f32x4 sacc[2][8];
#pragma unroll
        for (int m = 0; m < 2; m++)
#pragma unroll
          for (int n = 0; n < 8; n++) sacc[m][n] = (f32x4){0.f,0.f,0.f,0.f};
        for (int kk = 0; kk < 2; kk++) {
          bf16x8 a0 = *(const bf16x8*)&stg[((2*w) * 16 + fr) * 68 + kk * 32 + fg * 8];
          bf16x8 a1 = *(const bf16x8*)&stg[((2*w+1) * 16 + fr) * 68 + kk * 32 + fg * 8];
#pragma unroll
          for (int nt = 0; nt < 8; nt++) {
            int hd = half * 128 + nt * 16 + fr;
            bf16x8 bf_ = *(const bf16x8*)&Kc[(size_t)hd * 64 + kk * 32 + fg * 8];
            sacc[0][nt] = MFMA(a0, bf_, sacc[0][nt]);
            sacc[1][nt] = MFMA(a1, bf_, sacc[1][nt]);
          }
        }
#pragma unroll
        for (int m = 0; m < 2; m++) {
          int nrow0 = (2*w + m) * 16 + 4 * fg;
#pragma unroll
          for (int nt = 0; nt < 8; nt++) {
            int hd = half * 128 + nt * 16 + fr;
#pragma unroll
            for (int r = 0; r < 4; r++) {
              int ad = (nrow0 + r) * 264 + hd;
              float s = bf2f(Shi[ad]) + bf2f(Slo[ad]);
              s = l63 * s + sacc[m][nt][r];
              ushort hi = f2bf(s);
              Shi[ad] = hi;
              Slo[ad] = f2bf(s - bf2f(hi));
            }
          }
        }
      }
    }
    __syncthreads();  // bar4: S updated, O done
  }
}

// =====================================================================
// RMSNorm(DV) * o_norm_weight * SiLU(gate)
// =====================================================================
__global__ __launch_bounds__(256) void gate_kernel(float* __restrict__ o,
    const ushort* __restrict__ xg, const float* __restrict__ onw) {
  int wid = threadIdx.x >> 6, lane = threadIdx.x & 63;
  int row = (blockIdx.x << 2) + wid;
  if (row >= BL * NH) return;
  int t = row >> 3, h = row & 7;
  float* op = o + (size_t)t * VD + h * DV;
  const ushort* gp = xg + (size_t)t * VD + h * DV;
  float4 a0 = *(const float4*)&op[lane * 8];
  float4 a1 = *(const float4*)&op[lane * 8 + 4];
  float ss = a0.x*a0.x + a0.y*a0.y + a0.z*a0.z + a0.w*a0.w
           + a1.x*a1.x + a1.y*a1.y + a1.z*a1.z + a1.w*a1.w;
#pragma unroll
  for (int off = 32; off >= 1; off >>= 1) ss += __shfl_xor(ss, off, 64);
  float r = rsqrtf(ss * (1.f / DV) + 1e-5f);
  ushort4 gu0 = *(const ushort4*)&gp[lane * 8];
  ushort4 gu1 = *(const ushort4*)&gp[lane * 8 + 4];
  float4 n0 = *(const float4*)&onw[lane * 8];
  float4 n1 = *(const float4*)&onw[lane * 8 + 4];
  float g;
  g = bf2f(gu0.x); a0.x = a0.x * r * n0.x * (g * sigf(g));
  g = bf2f(gu0.y); a0.y = a0.y * r * n0.y * (g * sigf(g));
  g = bf2f(gu0.z); a0.z = a0.z * r * n0.z * (g * sigf(g));
  g = bf2f(gu0.w); a0.w = a0.w * r * n0.w * (g * sigf(g));
  g = bf2f(gu1.x); a1.x = a1.x * r * n1.x * (g * sigf(g));
  g = bf2f(gu1.y); a1.y = a1.y * r * n1.y * (g * sigf(g));
  g = bf2f(gu1.z); a1.z = a1.z * r * n1.z * (g * sigf(g));
  g = bf2f(gu1.w); a1.w = a1.w * r * n1.w * (g * sigf(g));
  *(float4*)&op[lane * 8]     = a0;
  *(float4*)&op[lane * 8 + 4] = a1;
}

// =====================================================================
extern "C" void kernel_launch(void* const* d_in, const int* in_sizes, int n_in,
                              void* d_out, int out_size, void* d_ws, size_t ws_size,
                              hipStream_t stream) {
  const float* x    = (const float*)d_in[0];
  const int*   modv = (const int*)d_in[1];
  const float* Wq   = (const float*)d_in[2];
  const float* Wk   = (const float*)d_in[3];
  const float* Wv   = (const float*)d_in[4];
  const float* cq   = (const float*)d_in[5];
  const float* ck   = (const float*)d_in[6];
  const float* cv   = (const float*)d_in[7];
  const float* Wek  = (const float*)d_in[8];
  const float* Wb   = (const float*)d_in[9];
  const float* Wa   = (const float*)d_in[10];
  const float* Alog = (const float*)d_in[11];
  const float* dtb  = (const float*)d_in[12];
  const float* ow   = (const float*)d_in[13];
  const float* Wg   = (const float*)d_in[14];
  const float* onw  = (const float*)d_in[15];
  const float* Wo   = (const float*)d_in[16];
  float* out = (float*)d_out;
  char* base = (char*)d_ws;

  // ---- static workspace layout (~189.5 MB; round-1 proved ws >= ~202 MB) ----
  ushort* xbf   = (ushort*)(base + 0);             // 8.4M; -> kbbf
  ushort* Wcat  = (ushort*)(base + 8388608);       // 50.3M (P1 only)
  ushort* kebf  = (ushort*)(base + 8388608);       // 25.2M (P3+)
  ushort* v_T   = (ushort*)(base + 33554432);      // 16.8M (P2+)
  ushort* Tb    = (ushort*)(base + 50331648);      // 6.3M  (P4+)
  ushort* xqb   = (ushort*)(base + 58720256);      // 8.4M; -> Pb
  ushort* Pb    = (ushort*)(base + 58720256);      // 6.3M
  ushort* xkb   = (ushort*)(base + 67108864);      // 8.4M; -> qbf
  ushort* qbf   = (ushort*)(base + 67108864);      // 8.4M
  ushort* xvb   = (ushort*)(base + 75497472);      // 16.8M; -> wobf
  ushort* wobf  = (ushort*)(base + 75497472);      // 16.8M
  ushort* xgb   = (ushort*)(base + 92274688);      // 16.8M (till gate)
  float*  qb    = (float*)(base + 109051904);      // 16.8M f32; -> obbf
  ushort* obbf  = (ushort*)(base + 109051904);     // 16.8M
  float*  kb    = (float*)(base + 125829120);      // 16.8M f32; region+spare -> KbarT
  ushort* KbarT = (ushort*)(base + 125829120);     // 25.2M
  float*  ob    = (float*)(base + 150994944);      // 33.6M
  ushort* wekbf = (ushort*)(base + 184549376);     // 3.1M
  float*  xba   = (float*)(base + 187695104);      // 393K
  float*  wba   = (float*)(base + 188088320);      // 393K
  float*  logdecb = (float*)(base + 188481536);    // 196K
  float*  bmb   = (float*)(base + 188678144);      // 196K
  float*  slamb = (float*)(base + 188874752);      // 196K
  float*  kscb  = (float*)(base + 189071360);      // 196K
  float*  woutb = (float*)(base + 189267968);      // 128B
  ushort* kbbf  = xbf;

  dim3 blk(256);
  // ---- bf16 conversions ----
  cvt_kernel<<<4096, blk, 0, stream>>>(x, xbf, BL * HS / 4);
  cvt4_kernel<<<24576, blk, 0, stream>>>(Wq, Wk, Wv, Wg, Wcat);
  cvt_kernel<<<1536, blk, 0, stream>>>(Wek, wekbf, NE * NH * HD * HD / 4);
  hipMemcpyAsync(wba, Wb, (size_t)24 * HS * 4, hipMemcpyDeviceToDevice, stream);
  hipMemcpyAsync(wba + (size_t)24 * HS, Wa, (size_t)24 * HS * 4, hipMemcpyDeviceToDevice, stream);
  // ---- fused q|k|v|g projection ----
  gemm_big_kernel<<<dim3(NCAT/128, BL/128), blk, 0, stream>>>(xbf, Wcat, xqb, xkb, xvb, xgb);
  // ---- gate projections (fp32, N=48) ----
  gemm_nt_kernel<<<dim3(1, BL/64), blk, 0, stream>>>(x, wba, xba, BL, 48, HS);
  // ---- conv + silu ----
  conv_silu_kernel<<<4096, blk, 0, stream>>>(xqb, cq, qb, KD, 0);
  conv_silu_kernel<<<4096, blk, 0, stream>>>(xkb, ck, kb, KD, 0);
  conv_v_t_kernel<<<dim3(VD/64, BL/64), blk, 0, stream>>>(xvb, cv, v_T);
  // ---- l2norm -> bf16 (q gets *HD^-0.5) ----
  l2norm_kernel<<<(BL*NH)/4, blk, 0, stream>>>(qb, qbf, 0.0625f, BL*NH, 1);
  l2norm_kernel<<<(BL*NH)/4, blk, 0, stream>>>(kb, kbbf, 1.0f, BL*NH, 1);
  // ---- Wo -> bf16 (xvb region dead) ----
  cvt_kernel<<<8192, blk, 0, stream>>>(Wo, wobf, HS * VD / 4);
  // ---- per-expert key transform (bf16 out) ----
  gemm_ke_kernel<<<dim3(HD/128, BL/128, NE*NH), blk, 0, stream>>>(kbbf, wekbf, kebf);
  // ---- gate scalars + expert mixing ----
  scalars_kernel<<<(BL*NE*NH + 255)/256, blk, 0, stream>>>(xba, modv, Alog, dtb, logdecb, bmb);
  wout_kernel<<<1, 64, 0, stream>>>(ow, woutb);
  // ---- chunk prep: T, P, scales; then KbarT ----
  prep_kernel<<<NEBH * NCHUNK, blk, 0, stream>>>(kebf, qbf, logdecb, bmb, Tb, Pb, slamb, kscb);
  kbar_kernel<<<NEBH * NCHUNK, blk, 0, stream>>>(kebf, kscb, KbarT);
  // ---- chunked MFMA scan ----
  hipMemsetAsync(ob, 0, (size_t)BL * VD * sizeof(float), stream);
  const int smem_bytes = 128*264*2*2 + 128*68*2 + 128*4;  // 153,088
  static int attr_set = 0;
  hipFuncSetAttribute((const void*)scan_mfma_kernel,
                      hipFuncAttributeMaxDynamicSharedMemorySize, smem_bytes);
  (void)attr_set;
  scan_mfma_kernel<<<NEBH * 4, 512, smem_bytes, stream>>>(
      kebf, qbf, v_T, Tb, Pb, KbarT, bmb, slamb, woutb, ob);
  // ---- RMSNorm * silu(gate) ----
  gate_kernel<<<(BL*NH)/4, blk, 0, stream>>>(ob, xgb, onw);
  // ---- output projection ----
  cvt_kernel<<<8192, blk, 0, stream>>>(ob, obbf, BL * VD / 4);
  gemm_wo_kernel<<<dim3(HS/128, BL/128), blk, 0, stream>>>(obbf, wobf, out);
}